// Round 1
// baseline (157.103 us; speedup 1.0000x reference)
//
#include <hip/hip_runtime.h>

// h0[row, col] = dot(feat[row, 0:25], Wmlp[0:25, col]);  64 cols, one thread each
__global__ __launch_bounds__(256) void k_h0(const float* __restrict__ feat,
                                            const float* __restrict__ Wmlp,
                                            float* __restrict__ h0, int N) {
    int t = blockIdx.x * blockDim.x + threadIdx.x;
    int row = t >> 6;
    int col = t & 63;
    if (row >= N) return;
    const float* f = feat + row * 25;
    float acc = 0.f;
#pragma unroll
    for (int k = 0; k < 25; ++k) acc += f[k] * Wmlp[k * 64 + col];
    h0[row * 64 + col] = acc;
}

// Layer 1 for ALL nodes: weighted1[i, 0:64]  = sum_r W1[c,r]    * mean_r[c]
//                        weighted1[i,64:128] = h0[i,c] - sum_r W1[64+c,r]*mean_r[c]
// (uses softmax row-sum == 1)
// One wave (64 lanes) per node, lane == column c. 4 nodes per 256-thread block.
__global__ __launch_bounds__(256) void k_layer1(const float* __restrict__ h0,
                                                const float* __restrict__ alpha1,
                                                const int* __restrict__ adj,
                                                float* __restrict__ w1, int N) {
    int wave = threadIdx.x >> 6;
    int lane = threadIdx.x & 63;
    int i = blockIdx.x * 4 + wave;
    if (i >= N) return;

    // lanes 0..31 hold the 32 neighbor indices for each relation
    int idxreg[3];
#pragma unroll
    for (int r = 0; r < 3; ++r)
        idxreg[r] = (lane < 32) ? adj[(r * N + i) * 32 + lane] : 0;

    float mean[3];
#pragma unroll
    for (int r = 0; r < 3; ++r) {
        float acc = 0.f;
#pragma unroll
        for (int k = 0; k < 32; ++k) {
            int nb = __shfl(idxreg[r], k, 64);
            acc += h0[nb * 64 + lane];   // coalesced 256B row read
        }
        mean[r] = acc * (1.f / 32.f);
    }

    // per-column softmax over the 3 relations (rows lane and 64+lane of alpha1)
    float et[3], eb[3], st = 0.f, sb = 0.f;
#pragma unroll
    for (int r = 0; r < 3; ++r) {
        et[r] = expf(alpha1[lane * 3 + r]);        st += et[r];
        eb[r] = expf(alpha1[(64 + lane) * 3 + r]); sb += eb[r];
    }
    float top = 0.f, bot = 0.f;
#pragma unroll
    for (int r = 0; r < 3; ++r) {
        top += et[r] * mean[r];
        bot += eb[r] * mean[r];
    }
    top /= st;
    bot /= sb;

    w1[i * 128 + lane]      = top;
    w1[i * 128 + 64 + lane] = h0[i * 64 + lane] - bot;
}

// Layer 2 + final projection for the 1024 batch nodes.
// h2 = [h0[i](64) | w1[i](128) | t2(128) | t3(128)], out = h2 @ lw + log(prior)
// One 128-thread block per batch node; thread t == column c in 0..127.
__global__ __launch_bounds__(128) void k_layer2(const float* __restrict__ h0,
                                                const float* __restrict__ w1,
                                                const float* __restrict__ alpha2,
                                                const float* __restrict__ lw,
                                                const float* __restrict__ prior,
                                                const int* __restrict__ adj,
                                                const int* __restrict__ nodes,
                                                float* __restrict__ out, int N) {
    __shared__ int s_idx[96];
    __shared__ float s_red[4];
    int b = blockIdx.x;
    int i = nodes[b];
    int t = threadIdx.x;

    if (t < 96) {
        int r = t >> 5, k = t & 31;
        s_idx[t] = adj[(r * N + i) * 32 + k];
    }
    __syncthreads();

    float mean[3];
#pragma unroll
    for (int r = 0; r < 3; ++r) {
        float acc = 0.f;
#pragma unroll
        for (int k = 0; k < 32; ++k)
            acc += w1[s_idx[r * 32 + k] * 128 + t];   // coalesced 512B row read
        mean[r] = acc * (1.f / 32.f);
    }

    float et[3], eb[3], st = 0.f, sb = 0.f;
#pragma unroll
    for (int r = 0; r < 3; ++r) {
        et[r] = expf(alpha2[t * 3 + r]);         st += et[r];
        eb[r] = expf(alpha2[(128 + t) * 3 + r]); sb += eb[r];
    }
    float t2 = 0.f, wb = 0.f;
#pragma unroll
    for (int r = 0; r < 3; ++r) {
        t2 += et[r] * mean[r];
        wb += eb[r] * mean[r];
    }
    t2 /= st;
    wb /= sb;

    float t1 = w1[i * 128 + t];
    float t3 = t1 - wb;

    // partial dot with linear_w [448,2] row-major
    float p0 = t1 * lw[(64 + t) * 2 + 0] + t2 * lw[(192 + t) * 2 + 0] + t3 * lw[(320 + t) * 2 + 0];
    float p1 = t1 * lw[(64 + t) * 2 + 1] + t2 * lw[(192 + t) * 2 + 1] + t3 * lw[(320 + t) * 2 + 1];
    if (t < 64) {
        float t0 = h0[i * 64 + t];
        p0 += t0 * lw[t * 2 + 0];
        p1 += t0 * lw[t * 2 + 1];
    }

    // wave reduce (width 64), then cross-wave via LDS
#pragma unroll
    for (int off = 32; off > 0; off >>= 1) {
        p0 += __shfl_down(p0, off, 64);
        p1 += __shfl_down(p1, off, 64);
    }
    int wave = t >> 6, lane = t & 63;
    if (lane == 0) {
        s_red[wave * 2 + 0] = p0;
        s_red[wave * 2 + 1] = p1;
    }
    __syncthreads();
    if (t == 0) {
        out[b * 2 + 0] = s_red[0] + s_red[2] + logf(prior[0]);
        out[b * 2 + 1] = s_red[1] + s_red[3] + logf(prior[1]);
    }
}

extern "C" void kernel_launch(void* const* d_in, const int* in_sizes, int n_in,
                              void* d_out, int out_size, void* d_ws, size_t ws_size,
                              hipStream_t stream) {
    const float* feat   = (const float*)d_in[0];  // [N,25]
    const float* Wmlp   = (const float*)d_in[1];  // [25,64]
    const float* alpha1 = (const float*)d_in[2];  // [128,3]
    const float* alpha2 = (const float*)d_in[3];  // [256,3]
    const float* lw     = (const float*)d_in[4];  // [448,2]
    const float* prior  = (const float*)d_in[5];  // [2]
    const int*   adj    = (const int*)d_in[6];    // [3,N,32]
    const int*   nodes  = (const int*)d_in[7];    // [B]
    float* out = (float*)d_out;

    int N = in_sizes[0] / 25;   // 50000
    int B = in_sizes[7];        // 1024

    float* h0 = (float*)d_ws;                 // [N,64]
    float* w1 = h0 + (size_t)N * 64;          // [N,128]

    k_h0    <<<(N * 64 + 255) / 256, 256, 0, stream>>>(feat, Wmlp, h0, N);
    k_layer1<<<(N + 3) / 4,          256, 0, stream>>>(h0, alpha1, adj, w1, N);
    k_layer2<<<B,                    128, 0, stream>>>(h0, w1, alpha2, lw, prior, adj, nodes, out, N);
}

// Round 2
// 73.074 us; speedup vs baseline: 2.1499x; 2.1499x over previous
//
#include <hip/hip_runtime.h>

typedef unsigned int u32;
typedef unsigned short u16;

__device__ __forceinline__ float bf16_lo(u32 u) { u32 x = u << 16; return __builtin_bit_cast(float, x); }
__device__ __forceinline__ float bf16_hi(u32 u) { u32 x = u & 0xffff0000u; return __builtin_bit_cast(float, x); }
__device__ __forceinline__ float bf16_one(u16 v) { u32 x = ((u32)v) << 16; return __builtin_bit_cast(float, x); }
__device__ __forceinline__ u16 f2bf(float f) {  // round-to-nearest-even
    u32 x = __builtin_bit_cast(u32, f);
    return (u16)((x + 0x7fffu + ((x >> 16) & 1u)) >> 16);
}

// h0[row,col] = dot(feat[row,:25], W[:25,col]); also emit featp = bf16(feat) padded to 32 cols.
__global__ __launch_bounds__(256) void k_h0(const float* __restrict__ feat,
                                            const float* __restrict__ W,
                                            float* __restrict__ h0,
                                            u16* __restrict__ featp, int N) {
    int t = blockIdx.x * 256 + threadIdx.x;
    int row = t >> 6;
    int col = t & 63;
    if (row >= N) return;
    const float* f = feat + row * 25;
    float acc = 0.f;
#pragma unroll
    for (int k = 0; k < 25; ++k) acc += f[k] * W[k * 64 + col];
    h0[row * 64 + col] = acc;
    if (col < 32) featp[row * 32 + col] = (col < 25) ? f2bf(f[col]) : (u16)0;
}

// Layer 1 for ALL nodes, gathering in FEAT space (64B bf16 rows, L2-resident):
//   meanfeat_r = mean_k featp[adj[r,i,k]]   (25 dims)
//   mean_r     = meanfeat_r @ W             (64 dims, via readlane broadcast)
//   w1h[i,c]    = bf16( sum_r W1t[c,r]*mean_r[c] )                  c<64
//   w1h[i,64+c] = bf16( h0[i,c] - sum_r W1b[c,r]*mean_r[c] )
// One wave per node; 16-lane group g handles neighbor slot it*4+g, lane&15 = column pair.
__global__ __launch_bounds__(256) void k_layer1(const float* __restrict__ h0,
                                                const u16* __restrict__ featp,
                                                const float* __restrict__ Wmlp,
                                                const float* __restrict__ alpha1,
                                                const int* __restrict__ adj,
                                                u16* __restrict__ w1h, int N) {
    int wave = threadIdx.x >> 6;
    int lane = threadIdx.x & 63;
    int i = blockIdx.x * 4 + wave;
    if (i >= N) return;
    int g = lane >> 4;    // neighbor subgroup 0..3
    int c = lane & 15;    // column-pair index: cols 2c, 2c+1

    // register-cache W column: wcol[k] = W[k][lane]
    float wcol[25];
#pragma unroll
    for (int k = 0; k < 25; ++k) wcol[k] = Wmlp[k * 64 + lane];

    const u32* fp = (const u32*)featp;  // 16 u32 per padded row

    float a0[3], a1[3];
#pragma unroll
    for (int r = 0; r < 3; ++r) {
        const int* arow = adj + ((size_t)r * N + i) * 32;
        float s0 = 0.f, s1 = 0.f;
#pragma unroll
        for (int it = 0; it < 8; ++it) {
            int nb = arow[it * 4 + g];          // 16 lanes share addr -> broadcast
            u32 u = fp[nb * 16 + c];            // 64B per group, coalesced
            s0 += bf16_lo(u);
            s1 += bf16_hi(u);
        }
        // reduce across the 4 subgroups (lanes with equal lane&15)
        s0 += __shfl_xor(s0, 16, 64); s0 += __shfl_xor(s0, 32, 64);
        s1 += __shfl_xor(s1, 16, 64); s1 += __shfl_xor(s1, 32, 64);
        a0[r] = s0; a1[r] = s1;
    }

    // mean_r[lane] = (1/32) * sum_k meanfeat_r[k] * W[k][lane]
    float mean[3];
#pragma unroll
    for (int r = 0; r < 3; ++r) {
        float acc = 0.f;
#pragma unroll
        for (int k = 0; k < 25; ++k) {
            int src = (k & 1) ? __builtin_bit_cast(int, a1[r]) : __builtin_bit_cast(int, a0[r]);
            float mf = __builtin_bit_cast(float, __builtin_amdgcn_readlane(src, k >> 1));
            acc += mf * wcol[k];
        }
        mean[r] = acc * (1.f / 32.f);
    }

    // per-column softmax over 3 relations
    float et[3], eb[3], st = 0.f, sb = 0.f;
#pragma unroll
    for (int r = 0; r < 3; ++r) {
        et[r] = __expf(alpha1[lane * 3 + r]);        st += et[r];
        eb[r] = __expf(alpha1[(64 + lane) * 3 + r]); sb += eb[r];
    }
    float top = 0.f, bot = 0.f;
#pragma unroll
    for (int r = 0; r < 3; ++r) { top += et[r] * mean[r]; bot += eb[r] * mean[r]; }
    top /= st;
    bot /= sb;

    float self = h0[i * 64 + lane];
    w1h[(size_t)i * 128 + lane]      = f2bf(top);
    w1h[(size_t)i * 128 + 64 + lane] = f2bf(self - bot);
}

// Layer 2 + final projection for the batch nodes. One 128-thread block per node.
__global__ __launch_bounds__(128) void k_layer2(const float* __restrict__ h0,
                                                const u16* __restrict__ w1h,
                                                const float* __restrict__ alpha2,
                                                const float* __restrict__ lw,
                                                const float* __restrict__ prior,
                                                const int* __restrict__ adj,
                                                const int* __restrict__ nodes,
                                                float* __restrict__ out, int N) {
    __shared__ int s_idx[96];
    __shared__ float s_red[4];
    int b = blockIdx.x;
    int i = nodes[b];
    int t = threadIdx.x;

    if (t < 96) {
        int r = t >> 5, k = t & 31;
        s_idx[t] = adj[((size_t)r * N + i) * 32 + k];
    }
    __syncthreads();

    float mean[3];
#pragma unroll
    for (int r = 0; r < 3; ++r) {
        float acc = 0.f;
#pragma unroll
        for (int k = 0; k < 32; ++k)
            acc += bf16_one(w1h[(size_t)s_idx[r * 32 + k] * 128 + t]);  // 256B coalesced
        mean[r] = acc * (1.f / 32.f);
    }

    float et[3], eb[3], st = 0.f, sb = 0.f;
#pragma unroll
    for (int r = 0; r < 3; ++r) {
        et[r] = __expf(alpha2[t * 3 + r]);         st += et[r];
        eb[r] = __expf(alpha2[(128 + t) * 3 + r]); sb += eb[r];
    }
    float t2 = 0.f, wb = 0.f;
#pragma unroll
    for (int r = 0; r < 3; ++r) { t2 += et[r] * mean[r]; wb += eb[r] * mean[r]; }
    t2 /= st;
    wb /= sb;

    float t1 = bf16_one(w1h[(size_t)i * 128 + t]);
    float t3 = t1 - wb;

    float p0 = t1 * lw[(64 + t) * 2 + 0] + t2 * lw[(192 + t) * 2 + 0] + t3 * lw[(320 + t) * 2 + 0];
    float p1 = t1 * lw[(64 + t) * 2 + 1] + t2 * lw[(192 + t) * 2 + 1] + t3 * lw[(320 + t) * 2 + 1];
    if (t < 64) {
        float t0 = h0[i * 64 + t];
        p0 += t0 * lw[t * 2 + 0];
        p1 += t0 * lw[t * 2 + 1];
    }

#pragma unroll
    for (int off = 32; off > 0; off >>= 1) {
        p0 += __shfl_down(p0, off, 64);
        p1 += __shfl_down(p1, off, 64);
    }
    int wv = t >> 6, lane = t & 63;
    if (lane == 0) { s_red[wv * 2 + 0] = p0; s_red[wv * 2 + 1] = p1; }
    __syncthreads();
    if (t == 0) {
        out[b * 2 + 0] = s_red[0] + s_red[2] + __logf(prior[0]);
        out[b * 2 + 1] = s_red[1] + s_red[3] + __logf(prior[1]);
    }
}

extern "C" void kernel_launch(void* const* d_in, const int* in_sizes, int n_in,
                              void* d_out, int out_size, void* d_ws, size_t ws_size,
                              hipStream_t stream) {
    const float* feat   = (const float*)d_in[0];  // [N,25]
    const float* Wmlp   = (const float*)d_in[1];  // [25,64]
    const float* alpha1 = (const float*)d_in[2];  // [128,3]
    const float* alpha2 = (const float*)d_in[3];  // [256,3]
    const float* lw     = (const float*)d_in[4];  // [448,2]
    const float* prior  = (const float*)d_in[5];  // [2]
    const int*   adj    = (const int*)d_in[6];    // [3,N,32]
    const int*   nodes  = (const int*)d_in[7];    // [B]
    float* out = (float*)d_out;

    int N = in_sizes[0] / 25;   // 50000
    int B = in_sizes[7];        // 1024

    float* h0   = (float*)d_ws;                    // [N,64]  f32   12.8 MB
    u16*   w1h  = (u16*)(h0 + (size_t)N * 64);     // [N,128] bf16  12.8 MB
    u16*   featp= w1h + (size_t)N * 128;           // [N,32]  bf16   3.2 MB

    k_h0    <<<(N * 64 + 255) / 256, 256, 0, stream>>>(feat, Wmlp, h0, featp, N);
    k_layer1<<<(N + 3) / 4,          256, 0, stream>>>(h0, featp, Wmlp, alpha1, adj, w1h, N);
    k_layer2<<<B,                    128, 0, stream>>>(h0, w1h, alpha2, lw, prior, adj, nodes, out, N);
}